// Round 11
// baseline (205.083 us; speedup 1.0000x reference)
//
#include <hip/hip_runtime.h>

#define F 64
#define NCH 256          // edge chunks (= blocks) for hist/scatter passes
// buckets are 256 nodes wide: bucket = dst >> 8. N=100000 -> NB=391
// packing: ebuf entry = src | (dst&255)<<17  (needs N < 131072)

typedef __attribute__((ext_vector_type(8))) short bf16x8;
typedef __attribute__((ext_vector_type(4))) float f32x4;

static __device__ __forceinline__ unsigned short f2bf(float f) {
    unsigned u = __float_as_uint(f);
    return (unsigned short)((u + 0x7fffu + ((u >> 16) & 1u)) >> 16);   // RNE
}
static __device__ __forceinline__ float bflo(unsigned u) { return __uint_as_float(u << 16); }
static __device__ __forceinline__ float bfhi(unsigned u) { return __uint_as_float(u & 0xffff0000u); }

// ---- pass A: per-chunk bucket histogram (blocks 0..NCH-1) + weight prep (last 2 blocks) ----
__global__ __launch_bounds__(256) void k_histprep(const int* __restrict__ dst,
                                                  int* __restrict__ histM,
                                                  const float* __restrict__ W1,
                                                  const float* __restrict__ W2,
                                                  unsigned short* __restrict__ W1t,
                                                  unsigned short* __restrict__ W2t,
                                                  int E, int chunk, int NB) {
    const int t = threadIdx.x;
    if (blockIdx.x >= NCH) {                 // weight prep: W -> bf16 transposed [n*64+k]
        int which = blockIdx.x - NCH;
        const float* W = which ? W2 : W1;
        unsigned short* Wt = which ? W2t : W1t;
#pragma unroll
        for (int i = 0; i < 16; ++i) {
            int e = t + i * 256;
            int n = e >> 6, k = e & 63;
            Wt[e] = f2bf(W[k * 64 + n]);
        }
        return;
    }
    extern __shared__ int h[];
    for (int i = t; i < NB; i += 256) h[i] = 0;
    __syncthreads();
    const int lo = blockIdx.x * chunk;
    const int hi = min(E, lo + chunk);
    for (int e = lo + t; e < hi; e += 256) {
        atomicAdd(&h[dst[e] >> 8], 1);
    }
    __syncthreads();
    for (int i = t; i < NB; i += 256) histM[i * NCH + blockIdx.x] = h[i];
}

// ---- 3-stage exclusive scan over M ints (tail guarded) ----
__global__ __launch_bounds__(256) void s_part(const int* __restrict__ v,
                                              int* __restrict__ part, int M) {
    __shared__ int sd[256];
    const int t = threadIdx.x;
    const int base = blockIdx.x * 1024 + t * 4;
    int s = 0;
    if (base + 3 < M) {
        int4 d = *(const int4*)&v[base];
        s = d.x + d.y + d.z + d.w;
    } else {
#pragma unroll
        for (int j = 0; j < 4; ++j) if (base + j < M) s += v[base + j];
    }
    sd[t] = s;
    __syncthreads();
    for (int off = 128; off > 0; off >>= 1) {
        if (t < off) sd[t] += sd[t + off];
        __syncthreads();
    }
    if (t == 0) part[blockIdx.x] = sd[0];
}

__global__ __launch_bounds__(256) void s_scanp(int* __restrict__ part, int nb) {
    __shared__ int sums[256];
    const int t = threadIdx.x;
    int s = (t < nb) ? part[t] : 0;          // nb <= 256
    sums[t] = s;
    __syncthreads();
    for (int off = 1; off < 256; off <<= 1) {
        int v = (t >= off) ? sums[t - off] : 0;
        __syncthreads();
        sums[t] += v;
        __syncthreads();
    }
    if (t < nb) part[t] = sums[t] - s;       // exclusive
}

__global__ __launch_bounds__(256) void s_emit(int* __restrict__ v,
                                              const int* __restrict__ part, int M) {
    __shared__ int sums[256];
    const int t = threadIdx.x;
    const int base = blockIdx.x * 1024 + t * 4;
    int d0 = 0, d1 = 0, d2 = 0, d3 = 0;
    if (base + 3 < M) {
        int4 d = *(const int4*)&v[base];
        d0 = d.x; d1 = d.y; d2 = d.z; d3 = d.w;
    } else {
        if (base + 0 < M) d0 = v[base + 0];
        if (base + 1 < M) d1 = v[base + 1];
        if (base + 2 < M) d2 = v[base + 2];
        if (base + 3 < M) d3 = v[base + 3];
    }
    int tot = d0 + d1 + d2 + d3;
    sums[t] = tot;
    __syncthreads();
    for (int off = 1; off < 256; off <<= 1) {
        int x = (t >= off) ? sums[t - off] : 0;
        __syncthreads();
        sums[t] += x;
        __syncthreads();
    }
    int o0 = part[blockIdx.x] + sums[t] - tot;
    int e0 = o0, e1 = o0 + d0, e2 = e1 + d1, e3 = e2 + d2;
    if (base + 3 < M) {
        *(int4*)&v[base] = make_int4(e0, e1, e2, e3);
    } else {
        int ee[4] = {e0, e1, e2, e3};
        for (int j = 0; j < 4; ++j) if (base + j < M) v[base + j] = ee[j];
    }
}

// ---- pass C: scatter packed edges into per-(bucket,block)-private regions ----
__global__ __launch_bounds__(256) void k_scatter2(const int* __restrict__ src,
                                                  const int* __restrict__ dst,
                                                  const int* __restrict__ scanM,
                                                  int* __restrict__ ebuf,
                                                  int E, int chunk, int NB) {
    extern __shared__ int cur[];
    const int t = threadIdx.x;
    for (int i = t; i < NB; i += 256) cur[i] = scanM[i * NCH + blockIdx.x];
    __syncthreads();
    const int lo = blockIdx.x * chunk;
    const int hi = min(E, lo + chunk);
    for (int e = lo + t; e < hi; e += 256) {
        int s = src[e];
        int d = dst[e];
        int p = atomicAdd(&cur[d >> 8], 1);
        ebuf[p] = s | ((d & 255) << 17);
    }
}

// ---- pass D: per-bucket LDS counting sort -> rowptr, dinv, node-sorted csr ----
__global__ __launch_bounds__(256) void k_csr(const int* __restrict__ ebuf,
                                             const int* __restrict__ scanM,
                                             int* __restrict__ rowptr,
                                             int* __restrict__ csr,
                                             float* __restrict__ dinv,
                                             int N, int E, int NB) {
    __shared__ int hist[256];
    __shared__ int scn[256];
    __shared__ int cur[256];
    const int t = threadIdx.x;
    const int bkt = blockIdx.x;
    const int beg = scanM[bkt * NCH];
    const int end = (bkt + 1 < NB) ? scanM[(bkt + 1) * NCH] : E;

    hist[t] = 0;
    __syncthreads();
    for (int e = beg + t; e < end; e += 256)
        atomicAdd(&hist[((unsigned)ebuf[e]) >> 17], 1);
    __syncthreads();

    scn[t] = hist[t];
    __syncthreads();
    for (int off = 1; off < 256; off <<= 1) {
        int v = (t >= off) ? scn[t - off] : 0;
        __syncthreads();
        scn[t] += v;
        __syncthreads();
    }

    {
        int excl = scn[t] - hist[t];
        int rp = beg + excl;
        int node = (bkt << 8) + t;
        cur[t] = rp;
        if (node < N) {
            rowptr[node] = rp;
            dinv[node] = rsqrtf((float)(hist[t] + 1));   // +1 self loop
        }
    }
    if (bkt == NB - 1 && t == 0) rowptr[N] = E;
    __syncthreads();

    for (int e = beg + t; e < end; e += 256) {
        int pk = ebuf[e];
        int p = atomicAdd(&cur[((unsigned)pk) >> 17], 1);
        csr[p] = pk & 0x1FFFF;
    }
}

// ---- hs1(bf16) = (X @ W1) * dinv[row] via MFMA (W1t pre-converted bf16) ----
__global__ __launch_bounds__(256) void k_gemm1(const float* __restrict__ X,
                                               const unsigned short* __restrict__ W1t,
                                               const float* __restrict__ dinv,
                                               unsigned short* __restrict__ hs, int N) {
    __shared__ unsigned short Wl[64 * 72];   // Wt[n][k], stride 72
    __shared__ unsigned short Xs[64 * 72];   // Xs[r][k], stride 72
    const int t = threadIdx.x;
    const int row0 = blockIdx.x * 64;

#pragma unroll
    for (int i = 0; i < 2; ++i) {
        int idx = t + i * 256;
        int n = idx >> 3, k = (idx & 7) * 8;
        *(uint4*)&Wl[n * 72 + k] = ((const uint4*)W1t)[idx];
    }
#pragma unroll
    for (int i = 0; i < 4; ++i) {
        int idx = t + i * 256;
        int r = idx >> 4, c = (idx & 15) * 4;
        int gr = row0 + r;
        float4 v = make_float4(0.f, 0.f, 0.f, 0.f);
        if (gr < N) v = *(const float4*)&X[(size_t)gr * F + c];
        unsigned p0 = (unsigned)f2bf(v.x) | ((unsigned)f2bf(v.y) << 16);
        unsigned p1 = (unsigned)f2bf(v.z) | ((unsigned)f2bf(v.w) << 16);
        *(uint2*)&Xs[r * 72 + c] = make_uint2(p0, p1);
    }
    __syncthreads();

    const int w    = t >> 6;
    const int lane = t & 63;
    const int l15  = lane & 15;
    const int quad = lane >> 4;

    bf16x8 bf[4][2];
#pragma unroll
    for (int ct = 0; ct < 4; ++ct)
#pragma unroll
        for (int kc = 0; kc < 2; ++kc)
            bf[ct][kc] = *(const bf16x8*)&Wl[(ct * 16 + l15) * 72 + kc * 32 + quad * 8];

    const int am = w * 16 + l15;
    bf16x8 af0 = *(const bf16x8*)&Xs[am * 72 + quad * 8];
    bf16x8 af1 = *(const bf16x8*)&Xs[am * 72 + 32 + quad * 8];

    f32x4 acc[4];
#pragma unroll
    for (int ct = 0; ct < 4; ++ct) {
        f32x4 z = {0.f, 0.f, 0.f, 0.f};
        z = __builtin_amdgcn_mfma_f32_16x16x32_bf16(af0, bf[ct][0], z, 0, 0, 0);
        z = __builtin_amdgcn_mfma_f32_16x16x32_bf16(af1, bf[ct][1], z, 0, 0, 0);
        acc[ct] = z;
    }

    float dv[4];
#pragma unroll
    for (int r = 0; r < 4; ++r) {
        int row = row0 + w * 16 + quad * 4 + r;
        dv[r] = (row < N) ? dinv[row] : 0.f;
    }
#pragma unroll
    for (int ct = 0; ct < 4; ++ct) {
#pragma unroll
        for (int r = 0; r < 4; ++r) {
            int row = row0 + w * 16 + quad * 4 + r;
            if (row < N)
                hs[(size_t)row * F + ct * 16 + l15] = f2bf(acc[ct][r] * dv[r]);
        }
    }
}

// ---- fused agg1 + gemm2: per-bucket gather -> relu(act1) in LDS -> @W2t -> hs2 ----
// hs2 emitted in SLICED layout: hs2[(slice*N + node)*16 + pos], slice=feature>>4.
__global__ __launch_bounds__(512) void k_aggmm(const unsigned short* __restrict__ hs1,
                                               const int* __restrict__ rowptr,
                                               const int* __restrict__ csr,
                                               const unsigned short* __restrict__ W2t,
                                               const float* __restrict__ b1,
                                               unsigned short* __restrict__ hs2, int N) {
    __shared__ unsigned short Act[256 * 72];   // act1 bf16, stride 72
    __shared__ unsigned short Wl[64 * 72];     // W2t padded
    __shared__ float sdv[256];                 // per-node dinv
    const int t = threadIdx.x;
    const int node0 = blockIdx.x << 8;

    {
        int idx = t;                           // 512 uint4 = full 4096 bf16
        int n = idx >> 3, k = (idx & 7) * 8;
        *(uint4*)&Wl[n * 72 + k] = ((const uint4*)W2t)[idx];
    }

    const int lane = t & 7;
    const int nsub = t >> 3;                   // 0..63
    const uint4* hsb = (const uint4*)hs1;
    float4 bb0 = *(const float4*)&b1[lane * 8];
    float4 bb1 = *(const float4*)&b1[lane * 8 + 4];

#pragma unroll
    for (int it = 0; it < 4; ++it) {
        int local = it * 64 + nsub;
        int node = node0 + local;
        float sc = 0.f;
        unsigned p0 = 0, p1 = 0, p2 = 0, p3 = 0;
        if (node < N) {
            int beg = rowptr[node];
            int end = rowptr[node + 1];
            sc = rsqrtf((float)(end - beg + 1));
            float a0, a1, a2, a3, a4, a5, a6, a7;
            {
                uint4 u = hsb[(size_t)node * 8 + lane];   // self loop
                a0 = bflo(u.x); a1 = bfhi(u.x);
                a2 = bflo(u.y); a3 = bfhi(u.y);
                a4 = bflo(u.z); a5 = bfhi(u.z);
                a6 = bflo(u.w); a7 = bfhi(u.w);
            }
            for (int base = beg; base < end; base += 16) {
                int i0 = base + lane;
                int i1 = base + 8 + lane;
                int x0 = (i0 < end) ? __builtin_nontemporal_load(&csr[i0]) : 0;
                int x1 = (i1 < end) ? __builtin_nontemporal_load(&csr[i1]) : 0;
                uint4 r[16];
#pragma unroll
                for (int k = 0; k < 8; ++k) {
                    int s = __shfl(x0, k, 8);
                    r[k] = hsb[(size_t)s * 8 + lane];
                }
#pragma unroll
                for (int k = 0; k < 8; ++k) {
                    int s = __shfl(x1, k, 8);
                    r[8 + k] = hsb[(size_t)s * 8 + lane];
                }
                int cnt = min(16, end - base);
#pragma unroll
                for (int k = 0; k < 16; ++k) {
                    if (k < cnt) {
                        uint4 u = r[k];
                        a0 += bflo(u.x); a1 += bfhi(u.x);
                        a2 += bflo(u.y); a3 += bfhi(u.y);
                        a4 += bflo(u.z); a5 += bfhi(u.z);
                        a6 += bflo(u.w); a7 += bfhi(u.w);
                    }
                }
            }
            float o0 = fmaxf(a0 * sc + bb0.x, 0.f), o1 = fmaxf(a1 * sc + bb0.y, 0.f);
            float o2 = fmaxf(a2 * sc + bb0.z, 0.f), o3 = fmaxf(a3 * sc + bb0.w, 0.f);
            float o4 = fmaxf(a4 * sc + bb1.x, 0.f), o5 = fmaxf(a5 * sc + bb1.y, 0.f);
            float o6 = fmaxf(a6 * sc + bb1.z, 0.f), o7 = fmaxf(a7 * sc + bb1.w, 0.f);
            p0 = (unsigned)f2bf(o0) | ((unsigned)f2bf(o1) << 16);
            p1 = (unsigned)f2bf(o2) | ((unsigned)f2bf(o3) << 16);
            p2 = (unsigned)f2bf(o4) | ((unsigned)f2bf(o5) << 16);
            p3 = (unsigned)f2bf(o6) | ((unsigned)f2bf(o7) << 16);
        }
        *(uint4*)&Act[local * 72 + lane * 8] = make_uint4(p0, p1, p2, p3);
        if (lane == 0) sdv[local] = sc;
    }
    __syncthreads();

    // phase 2: act1(bucket) @ W2, scale by dinv, emit hs2 (sliced layout)
    const int w    = t >> 6;                   // 8 waves
    const int l    = t & 63;
    const int l15  = l & 15;
    const int quad = l >> 4;

    bf16x8 bf[4][2];
#pragma unroll
    for (int nt = 0; nt < 4; ++nt)
#pragma unroll
        for (int kc = 0; kc < 2; ++kc)
            bf[nt][kc] = *(const bf16x8*)&Wl[(nt * 16 + l15) * 72 + kc * 32 + quad * 8];

#pragma unroll
    for (int mt = 0; mt < 2; ++mt) {
        int m0 = w * 32 + mt * 16;
        bf16x8 af0 = *(const bf16x8*)&Act[(m0 + l15) * 72 + quad * 8];
        bf16x8 af1 = *(const bf16x8*)&Act[(m0 + l15) * 72 + 32 + quad * 8];
#pragma unroll
        for (int nt = 0; nt < 4; ++nt) {
            f32x4 z = {0.f, 0.f, 0.f, 0.f};
            z = __builtin_amdgcn_mfma_f32_16x16x32_bf16(af0, bf[nt][0], z, 0, 0, 0);
            z = __builtin_amdgcn_mfma_f32_16x16x32_bf16(af1, bf[nt][1], z, 0, 0, 0);
#pragma unroll
            for (int r = 0; r < 4; ++r) {
                int row = m0 + quad * 4 + r;
                int node = node0 + row;
                if (node < N)
                    hs2[((size_t)nt * N + node) * 16 + l15] = f2bf(z[r] * sdv[row]);
            }
        }
    }
}

// ---- final aggregate, feature-sliced + nontemporal csr + 4-edge batch ----
// slice = blockIdx&3; panel 3.2MB stays L2-resident because csr streams via nt loads.
__global__ __launch_bounds__(256) void k_agg2(const unsigned short* __restrict__ hs2,
                                              const int* __restrict__ rowptr,
                                              const int* __restrict__ csr,
                                              const float* __restrict__ dinv,
                                              const float* __restrict__ b,
                                              float* __restrict__ out, int N) {
    const int slice = blockIdx.x & 3;
    const int chunk = blockIdx.x >> 2;
    const int t = threadIdx.x;
    const int node = chunk * 128 + (t >> 1);
    const int lane = t & 1;
    if (node >= N) return;
    const int beg = rowptr[node];
    const int end = rowptr[node + 1];
    const unsigned short* hp = hs2 + (size_t)slice * N * 16;

    float a[16];
#pragma unroll
    for (int j = 0; j < 16; ++j) a[j] = 0.f;

    for (int base = beg; base < end; base += 8) {
        int idx[4];
#pragma unroll
        for (int j = 0; j < 4; ++j) {
            int e = base + lane + j * 2;
            idx[j] = (e < end) ? __builtin_nontemporal_load(&csr[e]) : -1;
        }
        uint4 r0[4], r1[4];
#pragma unroll
        for (int j = 0; j < 4; ++j) {
            int s = (idx[j] >= 0) ? idx[j] : node;   // dummy: self row (L2-hot, discarded)
            const uint4* p = (const uint4*)(hp + (size_t)s * 16);
            r0[j] = p[0];
            r1[j] = p[1];
        }
#pragma unroll
        for (int j = 0; j < 4; ++j) {
            if (idx[j] >= 0) {
                uint4 u0 = r0[j], u1 = r1[j];
                a[0] += bflo(u0.x); a[1] += bfhi(u0.x);
                a[2] += bflo(u0.y); a[3] += bfhi(u0.y);
                a[4] += bflo(u0.z); a[5] += bfhi(u0.z);
                a[6] += bflo(u0.w); a[7] += bfhi(u0.w);
                a[8]  += bflo(u1.x); a[9]  += bfhi(u1.x);
                a[10] += bflo(u1.y); a[11] += bfhi(u1.y);
                a[12] += bflo(u1.z); a[13] += bfhi(u1.z);
                a[14] += bflo(u1.w); a[15] += bfhi(u1.w);
            }
        }
    }
#pragma unroll
    for (int j = 0; j < 16; ++j) a[j] += __shfl_xor(a[j], 1, 2);

    const float sc = dinv[node];
    const int j0 = lane * 8;                   // this lane writes features j0..j0+7
    uint4 sv = *(const uint4*)(hp + (size_t)node * 16 + j0);   // self loop
    float s0 = bflo(sv.x), s1 = bfhi(sv.x), s2 = bflo(sv.y), s3 = bfhi(sv.y);
    float s4 = bflo(sv.z), s5 = bfhi(sv.z), s6 = bflo(sv.w), s7 = bfhi(sv.w);
    float4 bb0 = *(const float4*)&b[slice * 16 + j0];
    float4 bb1 = *(const float4*)&b[slice * 16 + j0 + 4];
    float4 o0 = make_float4((a[j0 + 0] + s0) * sc + bb0.x,
                            (a[j0 + 1] + s1) * sc + bb0.y,
                            (a[j0 + 2] + s2) * sc + bb0.z,
                            (a[j0 + 3] + s3) * sc + bb0.w);
    float4 o1 = make_float4((a[j0 + 4] + s4) * sc + bb1.x,
                            (a[j0 + 5] + s5) * sc + bb1.y,
                            (a[j0 + 6] + s6) * sc + bb1.z,
                            (a[j0 + 7] + s7) * sc + bb1.w);
    float* op = &out[(size_t)node * F + slice * 16 + j0];
    *(float4*)op = o0;
    *(float4*)(op + 4) = o1;
}

extern "C" void kernel_launch(void* const* d_in, const int* in_sizes, int n_in,
                              void* d_out, int out_size, void* d_ws, size_t ws_size,
                              hipStream_t stream) {
    const float* x  = (const float*)d_in[0];
    const int*   ei = (const int*)d_in[1];
    const float* W1 = (const float*)d_in[2];
    const float* b1 = (const float*)d_in[3];
    const float* W2 = (const float*)d_in[4];
    const float* b2 = (const float*)d_in[5];
    float* out = (float*)d_out;

    const int N = in_sizes[0] / F;
    const int E = in_sizes[1] / 2;
    const int* src = ei;
    const int* dst = ei + E;

    const int NB = (N + 255) >> 8;                       // buckets (391)
    const int chunk = (E + NCH - 1) / NCH;
    const int M  = NB * NCH;
    const int Mp = ((M + 1023) / 1024) * 1024;
    const int nb2 = Mp / 1024;                           // <= 256

    // ws: W1t | W2t | dinv | part2 | rowptr | histM | ebuf | csr | hs1 | hs2
    char* ws = (char*)d_ws;
    size_t a = 0;
    unsigned short* W1t = (unsigned short*)(ws + a); a += (4096 * 2 + 255) & ~(size_t)255;
    unsigned short* W2t = (unsigned short*)(ws + a); a += (4096 * 2 + 255) & ~(size_t)255;
    float* dinv   = (float*)(ws + a); a += ((size_t)N * 4 + 255) & ~(size_t)255;
    int*   part2  = (int*)(ws + a);   a += ((size_t)nb2 * 4 + 255) & ~(size_t)255;
    int*   rowptr = (int*)(ws + a);   a += ((size_t)(N + 1) * 4 + 255) & ~(size_t)255;
    int*   histM  = (int*)(ws + a);   a += ((size_t)Mp * 4 + 255) & ~(size_t)255;
    int*   ebuf   = (int*)(ws + a);   a += ((size_t)E * 4 + 255) & ~(size_t)255;
    int*   csr    = (int*)(ws + a);   a += ((size_t)E * 4 + 255) & ~(size_t)255;
    unsigned short* hs1 = (unsigned short*)(ws + a); a += ((size_t)N * F * 2 + 255) & ~(size_t)255;
    unsigned short* hs2 = (unsigned short*)(ws + a);

    const size_t ldsNB = (size_t)NB * 4;
    const int gGemm = (N + 63) / 64;
    const int gAgg2 = ((N + 127) / 128) * 4;             // 4 slices

    // ---- CSR build ----
    k_histprep<<<NCH + 2, 256, ldsNB, stream>>>(dst, histM, W1, W2, W1t, W2t, E, chunk, NB);
    s_part<<<nb2, 256, 0, stream>>>(histM, part2, M);
    s_scanp<<<1, 256, 0, stream>>>(part2, nb2);
    s_emit<<<nb2, 256, 0, stream>>>(histM, part2, M);
    k_scatter2<<<NCH, 256, ldsNB, stream>>>(src, dst, histM, ebuf, E, chunk, NB);
    k_csr<<<NB, 256, 0, stream>>>(ebuf, histM, rowptr, csr, dinv, N, E, NB);

    // ---- layer 1 GEMM, fused agg1+gemm2, sliced final agg ----
    k_gemm1<<<gGemm, 256, 0, stream>>>(x, W1t, dinv, hs1, N);
    k_aggmm<<<NB, 512, 0, stream>>>(hs1, rowptr, csr, W2t, b1, hs2, N);
    k_agg2<<<gAgg2, 256, 0, stream>>>(hs2, rowptr, csr, dinv, b2, out, N);
}